// Round 2
// baseline (117431.348 us; speedup 1.0000x reference)
//
#include <hip/hip_runtime.h>
#include <hip/hip_cooperative_groups.h>

namespace cg = cooperative_groups;

// Problem constants
#define BB   32      // batch
#define TT_  512     // sequence length
#define DD   1024    // input dim
#define HH   1024    // hidden
#define RR_  64      // low-rank
#define FH   4096    // 4*H
#define TC   32      // timestep chunk (keeps workspace ~21 MB)

typedef __attribute__((ext_vector_type(8))) short          bf16x8;   // MFMA A/B frag (8 bf16)
typedef __attribute__((ext_vector_type(4))) float          f32x4;    // MFMA C/D frag
typedef __attribute__((ext_vector_type(4))) unsigned short us4;

// fp32 -> bf16 bits, round-to-nearest-even
__device__ __forceinline__ unsigned short f2bf(float x) {
    union { float f; unsigned u; } v; v.f = x;
    return (unsigned short)((v.u + 0x7FFFu + ((v.u >> 16) & 1u)) >> 16);
}

// ---------------------------------------------------------------------------
// Zero-init kernel for state buffers (ws is poisoned 0xAA before every call)
// ---------------------------------------------------------------------------
__global__ void init_zero(float4* p, int n4) {
    int i = blockIdx.x * blockDim.x + threadIdx.x;
    if (i < n4) p[i] = make_float4(0.f, 0.f, 0.f, 0.f);
}

// ---------------------------------------------------------------------------
// bf16-MFMA GEMM: C[m][n] = sum_k Arow(m)[k] * W[n][k] (+ bias[n]), fp32 I/O.
// Row m decomposes as m = tt*32 + b ; rowptr = Abase + (m>>5)*strideT + (m&31)*strideB
// fp32 inputs converted to bf16 (RNE) at LDS-staging time; fp32 accumulate.
// 256 threads = 4 waves in 2x2; each wave owns (BM/2)x(BN/2) via 16x16x32 MFMA.
// ---------------------------------------------------------------------------
template<int BM, int BN>
__global__ __launch_bounds__(256) void gemm_mfma(
    const float* __restrict__ Abase, long strideT, long strideB,
    const float* __restrict__ W, const float* __restrict__ bias,
    float* __restrict__ C, int M, int N, int K)
{
    constexpr int BK  = 32;
    constexpr int WTM = BM / 2, WTN = BN / 2;      // per-wave output tile
    constexpr int MI  = WTM / 16, NI = WTN / 16;   // 16x16 frags per wave
    constexpr int AU  = BM * (BK / 4) / 256;       // float4 staging units/thread
    constexpr int BU  = BN * (BK / 4) / 256;
    static_assert(BM * (BK / 4) % 256 == 0 && BN * (BK / 4) % 256 == 0, "staging");

    __shared__ __align__(16) unsigned short As[BM * BK];  // bf16 tile, 64B rows
    __shared__ __align__(16) unsigned short Bs[BN * BK];

    const int tid  = threadIdx.x;
    const int lane = tid & 63, wave = tid >> 6;
    const int wm   = wave >> 1, wn = wave & 1;     // 2x2 wave grid
    const int kg   = lane >> 4;                    // k-group 0..3
    const int lr   = lane & 15;
    const long bm  = (long)blockIdx.y * BM;
    const long bn  = (long)blockIdx.x * BN;

    const float* ag[AU]; int alds[AU];
    const float* bg[BU]; int blds[BU];
#pragma unroll
    for (int i = 0; i < AU; ++i) {
        int u = i * 256 + tid, row = u >> 3, uc = u & 7;   // 8 x 16B units per row
        long m = bm + row;
        ag[i]   = Abase + (m >> 5) * strideT + (m & 31) * strideB + uc * 4;
        alds[i] = row * BK + uc * 4;
    }
#pragma unroll
    for (int i = 0; i < BU; ++i) {
        int u = i * 256 + tid, row = u >> 3, uc = u & 7;
        bg[i]   = W + (long)(bn + row) * K + uc * 4;
        blds[i] = row * BK + uc * 4;
    }

    f32x4 acc[MI][NI] = {};

    float4 av[AU], bv[BU];
#pragma unroll
    for (int i = 0; i < AU; ++i) av[i] = *(const float4*)(ag[i]);
#pragma unroll
    for (int i = 0; i < BU; ++i) bv[i] = *(const float4*)(bg[i]);

    for (int k0 = 0; k0 < K; k0 += BK) {
        __syncthreads();
#pragma unroll
        for (int i = 0; i < AU; ++i) {
            us4 t; t.x = f2bf(av[i].x); t.y = f2bf(av[i].y);
                   t.z = f2bf(av[i].z); t.w = f2bf(av[i].w);
            *(us4*)&As[alds[i]] = t;
        }
#pragma unroll
        for (int i = 0; i < BU; ++i) {
            us4 t; t.x = f2bf(bv[i].x); t.y = f2bf(bv[i].y);
                   t.z = f2bf(bv[i].z); t.w = f2bf(bv[i].w);
            *(us4*)&Bs[blds[i]] = t;
        }
        __syncthreads();

        if (k0 + BK < K) {
#pragma unroll
            for (int i = 0; i < AU; ++i) av[i] = *(const float4*)(ag[i] + k0 + BK);
#pragma unroll
            for (int i = 0; i < BU; ++i) bv[i] = *(const float4*)(bg[i] + k0 + BK);
        }

        bf16x8 af[MI], bfr[NI];
#pragma unroll
        for (int mi = 0; mi < MI; ++mi)
            af[mi] = *(const bf16x8*)&As[(wm * WTM + mi * 16 + lr) * BK + kg * 8];
#pragma unroll
        for (int ni = 0; ni < NI; ++ni)
            bfr[ni] = *(const bf16x8*)&Bs[(wn * WTN + ni * 16 + lr) * BK + kg * 8];
#pragma unroll
        for (int mi = 0; mi < MI; ++mi)
#pragma unroll
            for (int ni = 0; ni < NI; ++ni)
                acc[mi][ni] = __builtin_amdgcn_mfma_f32_16x16x32_bf16(
                    af[mi], bfr[ni], acc[mi][ni], 0, 0, 0);
    }

    const int rbase = (lane >> 4) * 4;
#pragma unroll
    for (int mi = 0; mi < MI; ++mi) {
        long m = bm + wm * WTM + mi * 16 + rbase;
#pragma unroll
        for (int ni = 0; ni < NI; ++ni) {
            long n = bn + wn * WTN + ni * 16 + lr;
            float bia = bias ? bias[n] : 0.f;
#pragma unroll
            for (int r = 0; r < 4; ++r)
                C[(m + r) * (long)N + n] = acc[mi][ni][r] + bia;
        }
    }
}

// ---------------------------------------------------------------------------
// Persistent sLSTM scan over one chunk of TC steps. Cooperative launch:
// 256 blocks x 256 threads (1 block/CU). Per-step structure identical to the
// proven slstm_step kernel; grid.sync() replaces the kernel boundary.
// h double-buffer parity: t0 is always even, so (tt&1) selects like (t&1).
// ---------------------------------------------------------------------------
__global__ __launch_bounds__(256) void slstm_scan(
    const float* __restrict__ xw0,   // xwbuf, [tt][b][4H]
    const float* __restrict__ U,     // [4H][H]
    const float* __restrict__ bU,    // [4H]
    const float* __restrict__ alpha, // [H]
    float* __restrict__ h0,          // hA (hT layout)
    float* __restrict__ h1,          // hB
    float* __restrict__ cst,         // [B][H] in-place
    float* __restrict__ out1c)       // [tt][b][H]
{
    cg::grid_group grid = cg::this_grid();
    __shared__ float4 hs[64 * 32];   // 32 KB: quarter of h
    __shared__ float  zs[16][32];
    const int tid = threadIdx.x;
    const int b = tid & 31, rr = tid >> 5;      // rr 0..7
    const int j0 = blockIdx.x * 4;
    const int g0 = rr >> 2, jj0 = rr & 3;
    const float4* U0 = (const float4*)(U + (long)(g0 * HH + j0 + jj0) * HH);
    const float4* U1 = (const float4*)(U + (long)((g0 + 2) * HH + j0 + jj0) * HH);

    for (int tt = 0; tt < TC; ++tt) {
        const float* xw = xw0 + (long)tt * BB * FH;
        const float4* hin4 = (const float4*)((tt & 1) ? h1 : h0);
        float* hout       = (tt & 1) ? h0 : h1;
        float* out1t      = out1c + (long)tt * BB * HH;

        float acc0 = 0.f, acc1 = 0.f;
        for (int ph = 0; ph < 4; ++ph) {
            const int base = ph * 2048;
            for (int i = tid; i < 2048; i += 256) hs[i] = hin4[base + i];
            __syncthreads();
#pragma unroll 8
            for (int dd = 0; dd < 64; ++dd) {
                const int d4 = ph * 64 + dd;
                float4 hv = hs[dd * 32 + b];
                float4 u0 = U0[d4];
                float4 u1 = U1[d4];
                acc0 += u0.x * hv.x + u0.y * hv.y + u0.z * hv.z + u0.w * hv.w;
                acc1 += u1.x * hv.x + u1.y * hv.y + u1.z * hv.z + u1.w * hv.w;
            }
            __syncthreads();
        }
        zs[rr][b] = acc0;
        zs[rr + 8][b] = acc1;
        __syncthreads();

        if (tid < 128) {
            const int b2 = tid & 31, jj = tid >> 5;
            const int j = j0 + jj;
            const long xb = (long)b2 * FH;
            float zi = xw[xb + j]            + zs[jj][b2]      + bU[j];
            float zf = xw[xb + HH + j]       + zs[4 + jj][b2]  + bU[HH + j];
            float zo = xw[xb + 2 * HH + j]   + zs[8 + jj][b2]  + bU[2 * HH + j];
            float zg = xw[xb + 3 * HH + j]   + zs[12 + jj][b2] + bU[3 * HH + j];
            float ig = 1.f / (1.f + expf(-zi));
            float fg = 1.f / (1.f + expf(-zf));
            float og = 1.f / (1.f + expf(-zo));
            float g  = tanhf(zg);
            float cold = cst[b2 * HH + j];
            float cn = alpha[j] * (fg * cold + ig * g);
            float hn = og * tanhf(cn);
            cst[b2 * HH + j] = cn;
            hout[((long)blockIdx.x * 32 + b2) * 4 + jj] = hn;
            out1t[(long)b2 * HH + j] = hn;
        }
        __threadfence();
        grid.sync();
    }
}

// ---------------------------------------------------------------------------
// Persistent mLSTM scan over one chunk. Per step:
//   phase Q: distributed q[b][r] = xa*(h@Bm.T) — block bl owns 8 (b,r) pairs
//            (b = bl>>3, r = (bl&7)*8 + p), half-wave per pair. grid.sync.
//   phase Z: identical to proven mlstm_step (dots + gates + low-rank mix).
//   grid.sync (h_t visible for next step's phase Q).
// ---------------------------------------------------------------------------
__global__ __launch_bounds__(256) void mlstm_scan(
    const float* __restrict__ xw0,   // xwbuf, [tt][b][4H]
    const float* __restrict__ U,     // Um [4H][H]
    const float* __restrict__ bU,
    const float* __restrict__ P,     // [H][R]
    const float* __restrict__ Bm,    // [R][H]
    const float* __restrict__ xac0,  // [tt][b][R]
    float* __restrict__ q,           // [B][R]
    float* __restrict__ h0,          // hmA (hT layout)
    float* __restrict__ h1,          // hmB
    float* __restrict__ cst,
    float* __restrict__ out,         // [B][T][H] fp32
    int t0)
{
    cg::grid_group grid = cg::this_grid();
    __shared__ float4 hs[64 * 32];
    __shared__ float  zs[16][32];
    const int tid = threadIdx.x;
    const int b = tid & 31, rr = tid >> 5;
    const int j0 = blockIdx.x * 4;
    const int g0 = rr >> 2, jj0 = rr & 3;
    const float4* U0 = (const float4*)(U + (long)(g0 * HH + j0 + jj0) * HH);
    const float4* U1 = (const float4*)(U + (long)((g0 + 2) * HH + j0 + jj0) * HH);

    // q-phase fixed mapping: block owns batch qb, rows qr0..qr0+7
    const int qb  = blockIdx.x >> 3;
    const int qr0 = (blockIdx.x & 7) * 8;
    const int lane = tid & 63, wave = tid >> 6;
    const int half = lane >> 5, l = lane & 31;
    const int qr = qr0 + wave * 2 + half;          // this half-wave's r
    const float4* bm4 = (const float4*)(Bm + (long)qr * HH);

    for (int tt = 0; tt < TC; ++tt) {
        const float* xw  = xw0 + (long)tt * BB * FH;
        const float* xat = xac0 + (long)tt * BB * RR_;
        const float4* hin4 = (const float4*)((tt & 1) ? h1 : h0);
        float* hout       = (tt & 1) ? h0 : h1;
        const int t = t0 + tt;

        // ---- phase Q: q[qb][qr] = xa_t[qb][qr] * dot(h[qb], Bm[qr]) ----
        {
            float acc = 0.f;
#pragma unroll
            for (int i = 0; i < 8; ++i) {
                const int d4 = l * 8 + i;
                float4 hv = hin4[d4 * 32 + qb];
                float4 bv = bm4[d4];
                acc += hv.x * bv.x + hv.y * bv.y + hv.z * bv.z + hv.w * bv.w;
            }
#pragma unroll
            for (int off = 16; off; off >>= 1) acc += __shfl_down(acc, off, 32);
            if (l == 0) q[qb * RR_ + qr] = acc * xat[qb * RR_ + qr];
        }
        __threadfence();
        grid.sync();

        // ---- phase Z: dots + gates + low-rank mix (same as mlstm_step) ----
        float acc0 = 0.f, acc1 = 0.f;
        for (int ph = 0; ph < 4; ++ph) {
            const int base = ph * 2048;
            for (int i = tid; i < 2048; i += 256) hs[i] = hin4[base + i];
            __syncthreads();
#pragma unroll 8
            for (int dd = 0; dd < 64; ++dd) {
                const int d4 = ph * 64 + dd;
                float4 hv = hs[dd * 32 + b];
                float4 u0 = U0[d4];
                float4 u1 = U1[d4];
                acc0 += u0.x * hv.x + u0.y * hv.y + u0.z * hv.z + u0.w * hv.w;
                acc1 += u1.x * hv.x + u1.y * hv.y + u1.z * hv.z + u1.w * hv.w;
            }
            __syncthreads();
        }
        zs[rr][b] = acc0;
        zs[rr + 8][b] = acc1;
        __syncthreads();

        if (tid < 128) {
            const int b2 = tid & 31, jj = tid >> 5;
            const int j = j0 + jj;
            const long xb = (long)b2 * FH;
            float zi = xw[xb + j]          + zs[jj][b2]      + bU[j];
            float zf = xw[xb + HH + j]     + zs[4 + jj][b2]  + bU[HH + j];
            float zo = xw[xb + 2 * HH + j] + zs[8 + jj][b2]  + bU[2 * HH + j];
            float zg = xw[xb + 3 * HH + j] + zs[12 + jj][b2] + bU[3 * HH + j];
            float ig = 1.f / (1.f + expf(-zi));
            float fg = 1.f / (1.f + expf(-zf));
            float og = 1.f / (1.f + expf(-zo));
            float g  = tanhf(zg);
            float mx = 0.f;
            const float4* Pj = (const float4*)(P + (long)j * RR_);
            const float4* qb4 = (const float4*)(q + (long)b2 * RR_);
#pragma unroll
            for (int r4 = 0; r4 < 16; ++r4) {
                float4 pv = Pj[r4], qv = qb4[r4];
                mx += pv.x * qv.x + pv.y * qv.y + pv.z * qv.z + pv.w * qv.w;
            }
            float cold = cst[b2 * HH + j];
            float cn = fg * cold + ig * g + 0.1f * mx;
            float hn = og * tanhf(cn);
            cst[b2 * HH + j] = cn;
            hout[((long)blockIdx.x * 32 + b2) * 4 + jj] = hn;
            out[(long)b2 * (TT_ * HH) + (long)t * HH + j] = hn;
        }
        __threadfence();
        grid.sync();
    }
}

// ---------------------------------------------------------------------------
// Launch: chunked pipeline. GEMMs on bf16 MFMA; scans as persistent
// cooperative kernels (1 per chunk per scan). 81 launches total.
// ---------------------------------------------------------------------------
extern "C" void kernel_launch(void* const* d_in, const int* in_sizes, int n_in,
                              void* d_out, int out_size, void* d_ws, size_t ws_size,
                              hipStream_t stream) {
    const float* x     = (const float*)d_in[0];
    const float* Ws    = (const float*)d_in[1];
    const float* bWs   = (const float*)d_in[2];
    const float* Us    = (const float*)d_in[3];
    const float* bUs   = (const float*)d_in[4];
    const float* alpha = (const float*)d_in[5];
    const float* Wm    = (const float*)d_in[6];
    const float* bWm   = (const float*)d_in[7];
    const float* Um    = (const float*)d_in[8];
    const float* bUm   = (const float*)d_in[9];
    const float* A     = (const float*)d_in[10];
    const float* Bm    = (const float*)d_in[11];
    const float* P     = (const float*)d_in[12];
    float* out = (float*)d_out;

    float* w      = (float*)d_ws;
    float* xwbuf  = w;                               // TC*B*4H = 4,194,304 f (16 MB)
    float* out1c  = xwbuf + (long)TC * BB * FH;      // TC*B*H  = 1,048,576 f (4 MB)
    float* xac    = out1c + (long)TC * BB * HH;      // TC*B*R  = 65,536 f (256 KB)
    float* hA     = xac + (long)TC * BB * RR_;       // states: 32768 f each
    float* hB     = hA + BB * HH;
    float* cS     = hB + BB * HH;
    float* hmA    = cS + BB * HH;
    float* hmB    = hmA + BB * HH;
    float* cM     = hmB + BB * HH;
    float* q      = cM + BB * HH;                    // 2048 f
    // total: 5,506,048 floats = 21.0 MB

    // zero state buffers (hA..q): 6*32768 + 2048 = 198656 floats = 49664 float4
    init_zero<<<194, 256, 0, stream>>>((float4*)hA, 49664);

    dim3 gbig(FH / 128, (TC * BB) / 64);   // (32, 16) = 512 blocks
    dim3 gxa(RR_ / 64, (TC * BB) / 64);    // (1, 16)

    for (int ch = 0; ch < TT_ / TC; ++ch) {
        const int t0 = ch * TC;

        // ---- sLSTM: xw = x_chunk @ Ws.T + bWs (bf16 MFMA) ----
        gemm_mfma<64, 128><<<gbig, 256, 0, stream>>>(
            x + (long)t0 * DD, (long)DD, (long)TT_ * DD, Ws, bWs,
            xwbuf, TC * BB, FH, DD);

        // ---- persistent sLSTM scan over the chunk ----
        {
            const float* a0 = xwbuf; const float* a1 = Us; const float* a2 = bUs;
            const float* a3 = alpha; float* a4 = hA; float* a5 = hB;
            float* a6 = cS; float* a7 = out1c;
            void* args[] = {&a0, &a1, &a2, &a3, &a4, &a5, &a6, &a7};
            hipLaunchCooperativeKernel((void*)slstm_scan, dim3(256), dim3(256),
                                       args, 0, stream);
        }

        // ---- mLSTM projections for this chunk ----
        gemm_mfma<64, 128><<<gbig, 256, 0, stream>>>(
            out1c, (long)BB * HH, (long)HH, Wm, bWm,
            xwbuf, TC * BB, FH, HH);
        gemm_mfma<64, 64><<<gxa, 256, 0, stream>>>(
            out1c, (long)BB * HH, (long)HH, A, nullptr,
            xac, TC * BB, RR_, HH);

        // ---- persistent mLSTM scan over the chunk ----
        {
            const float* a0 = xwbuf; const float* a1 = Um; const float* a2 = bUm;
            const float* a3 = P; const float* a4 = Bm; const float* a5 = xac;
            float* a6 = q; float* a7 = hmA; float* a8 = hmB; float* a9 = cM;
            float* a10 = out; int a11 = t0;
            void* args[] = {&a0, &a1, &a2, &a3, &a4, &a5, &a6, &a7, &a8, &a9,
                            &a10, &a11};
            hipLaunchCooperativeKernel((void*)mlstm_scan, dim3(256), dim3(256),
                                       args, 0, stream);
        }
    }
}

// Round 3
// 12804.768 us; speedup vs baseline: 9.1709x; 9.1709x over previous
//
#include <hip/hip_runtime.h>

// Problem constants
#define BB   32      // batch
#define TT_  512     // sequence length
#define DD   1024    // input dim
#define HH   1024    // hidden
#define RR_  64      // low-rank
#define FH   4096    // 4*H
#define TC   32      // timestep chunk

typedef __attribute__((ext_vector_type(8))) short          bf16x8;   // MFMA A/B frag
typedef __attribute__((ext_vector_type(4))) float          f32x4;    // MFMA C/D frag
typedef __attribute__((ext_vector_type(4))) unsigned short us4;

// fp32 -> bf16 bits, round-to-nearest-even
__device__ __forceinline__ unsigned short f2bf(float x) {
    union { float f; unsigned u; } v; v.f = x;
    return (unsigned short)((v.u + 0x7FFFu + ((v.u >> 16) & 1u)) >> 16);
}

// ---------------------------------------------------------------------------
// Zero-init (ws poisoned 0xAA before every call)
// ---------------------------------------------------------------------------
__global__ void init_zero(float4* p, int n4) {
    int i = blockIdx.x * blockDim.x + threadIdx.x;
    if (i < n4) p[i] = make_float4(0.f, 0.f, 0.f, 0.f);
}

// fp32 -> bf16 bulk convert (for U matrices / Bm, done once per call)
__global__ void cvt_bf16(const float* __restrict__ src,
                         unsigned short* __restrict__ dst, int n4) {
    int i = blockIdx.x * blockDim.x + threadIdx.x;
    int stride = gridDim.x * blockDim.x;
    for (; i < n4; i += stride) {
        float4 v = ((const float4*)src)[i];
        us4 t; t.x = f2bf(v.x); t.y = f2bf(v.y); t.z = f2bf(v.z); t.w = f2bf(v.w);
        ((us4*)dst)[i] = t;
    }
}

// ---------------------------------------------------------------------------
// bf16-MFMA GEMM, fp32 I/O, TRANSPOSED output: C[m>>5][n][m&31]  (= [tt][n][b])
// Row m = tt*32 + b ; rowptr = Abase + (m>>5)*strideT + (m&31)*strideB
// ---------------------------------------------------------------------------
template<int BM, int BN>
__global__ __launch_bounds__(256) void gemm_mfma(
    const float* __restrict__ Abase, long strideT, long strideB,
    const float* __restrict__ W, const float* __restrict__ bias,
    float* __restrict__ C, int M, int N, int K)
{
    constexpr int BK  = 32;
    constexpr int WTM = BM / 2, WTN = BN / 2;
    constexpr int MI  = WTM / 16, NI = WTN / 16;
    constexpr int AU  = BM * (BK / 4) / 256;
    constexpr int BU  = BN * (BK / 4) / 256;

    __shared__ __align__(16) unsigned short As[BM * BK];
    __shared__ __align__(16) unsigned short Bs[BN * BK];

    const int tid  = threadIdx.x;
    const int lane = tid & 63, wave = tid >> 6;
    const int wm   = wave >> 1, wn = wave & 1;
    const int kg   = lane >> 4;
    const int lr   = lane & 15;
    const long bm  = (long)blockIdx.y * BM;
    const long bn  = (long)blockIdx.x * BN;

    const float* ag[AU]; int alds[AU];
    const float* bg[BU]; int blds[BU];
#pragma unroll
    for (int i = 0; i < AU; ++i) {
        int u = i * 256 + tid, row = u >> 3, uc = u & 7;
        long m = bm + row;
        ag[i]   = Abase + (m >> 5) * strideT + (m & 31) * strideB + uc * 4;
        alds[i] = row * BK + uc * 4;
    }
#pragma unroll
    for (int i = 0; i < BU; ++i) {
        int u = i * 256 + tid, row = u >> 3, uc = u & 7;
        bg[i]   = W + (long)(bn + row) * K + uc * 4;
        blds[i] = row * BK + uc * 4;
    }

    f32x4 acc[MI][NI] = {};

    float4 av[AU], bv[BU];
#pragma unroll
    for (int i = 0; i < AU; ++i) av[i] = *(const float4*)(ag[i]);
#pragma unroll
    for (int i = 0; i < BU; ++i) bv[i] = *(const float4*)(bg[i]);

    for (int k0 = 0; k0 < K; k0 += BK) {
        __syncthreads();
#pragma unroll
        for (int i = 0; i < AU; ++i) {
            us4 t; t.x = f2bf(av[i].x); t.y = f2bf(av[i].y);
                   t.z = f2bf(av[i].z); t.w = f2bf(av[i].w);
            *(us4*)&As[alds[i]] = t;
        }
#pragma unroll
        for (int i = 0; i < BU; ++i) {
            us4 t; t.x = f2bf(bv[i].x); t.y = f2bf(bv[i].y);
                   t.z = f2bf(bv[i].z); t.w = f2bf(bv[i].w);
            *(us4*)&Bs[blds[i]] = t;
        }
        __syncthreads();

        if (k0 + BK < K) {
#pragma unroll
            for (int i = 0; i < AU; ++i) av[i] = *(const float4*)(ag[i] + k0 + BK);
#pragma unroll
            for (int i = 0; i < BU; ++i) bv[i] = *(const float4*)(bg[i] + k0 + BK);
        }

        bf16x8 af[MI], bfr[NI];
#pragma unroll
        for (int mi = 0; mi < MI; ++mi)
            af[mi] = *(const bf16x8*)&As[(wm * WTM + mi * 16 + lr) * BK + kg * 8];
#pragma unroll
        for (int ni = 0; ni < NI; ++ni)
            bfr[ni] = *(const bf16x8*)&Bs[(wn * WTN + ni * 16 + lr) * BK + kg * 8];
#pragma unroll
        for (int mi = 0; mi < MI; ++mi)
#pragma unroll
            for (int ni = 0; ni < NI; ++ni)
                acc[mi][ni] = __builtin_amdgcn_mfma_f32_16x16x32_bf16(
                    af[mi], bfr[ni], acc[mi][ni], 0, 0, 0);
    }

    // Transposed epilogue: C[(m>>5)*N + n)*32 + (m&31)], float4 over 4 consecutive m.
    const int rbase = (lane >> 4) * 4;
#pragma unroll
    for (int mi = 0; mi < MI; ++mi) {
        long m0 = bm + wm * WTM + mi * 16 + rbase;
        long tt = m0 >> 5; int bq = (int)(m0 & 31);
#pragma unroll
        for (int ni = 0; ni < NI; ++ni) {
            long n = bn + wn * WTN + ni * 16 + lr;
            float bia = bias ? bias[n] : 0.f;
            float4 v = make_float4(acc[mi][ni][0] + bia, acc[mi][ni][1] + bia,
                                   acc[mi][ni][2] + bia, acc[mi][ni][3] + bia);
            *(float4*)&C[(tt * N + n) * 32 + bq] = v;
        }
    }
}

// ---------------------------------------------------------------------------
// sLSTM step, MFMA edition. Grid 64 x 256 (4 waves). Block owns j0..j0+15.
// Wave g computes Z-tile for gate g: rows g*H+j0..+15, all 32 batches.
// h carried as bf16 [32][1024]; staged in LDS with XOR-swizzle (G4).
// ---------------------------------------------------------------------------
__global__ __launch_bounds__(256) void slstm_step2(
    const float* __restrict__ xwT,          // [4096][32] fp32 (incl. bWs)
    const unsigned short* __restrict__ Ubf, // [4096][1024] bf16
    const float* __restrict__ bU,
    const float* __restrict__ alpha,
    const unsigned short* __restrict__ hin, // [32][1024] bf16
    unsigned short* __restrict__ hout,      // [32][1024] bf16
    float* __restrict__ cst,                // [32][1024]
    float* __restrict__ out1t)              // [32][1024] fp32
{
    __shared__ __align__(16) unsigned short hs[32 * 1024]; // 64 KB, swizzled
    __shared__ float zsl[4][16][32];                       // 8 KB
    const int tid  = threadIdx.x;
    const int lane = tid & 63, wv = tid >> 6;
    const int j0   = blockIdx.x * 16;
    const int lr   = lane & 15;
    const int koff = (lane >> 4) << 3;

    // stage h (64KB): 4096 x 16B units, swizzle byte^=((row&7)<<4)
    const uint4* hg = (const uint4*)hin;
#pragma unroll
    for (int i = 0; i < 16; ++i) {
        int u = tid + (i << 8);
        int o = u << 4;
        int sw = o ^ (((o >> 11) & 7) << 4);
        *(uint4*)((char*)hs + sw) = hg[u];
    }
    __syncthreads();

    const unsigned short* Arow =
        Ubf + (((long)(wv * HH + j0 + lr)) << 10) + koff;
    const int base0 = lr * 2048 + koff * 2;
    const int base1 = (lr + 16) * 2048 + koff * 2;
    const int swz   = (lr & 7) << 4;

    f32x4 accZ0 = {0.f, 0.f, 0.f, 0.f}, accZ1 = {0.f, 0.f, 0.f, 0.f};
#pragma unroll 4
    for (int k0 = 0; k0 < 1024; k0 += 32) {
        bf16x8 a  = *(const bf16x8*)(Arow + k0);
        bf16x8 b0 = *(const bf16x8*)((const char*)hs + ((base0 + k0 * 2) ^ swz));
        bf16x8 b1 = *(const bf16x8*)((const char*)hs + ((base1 + k0 * 2) ^ swz));
        accZ0 = __builtin_amdgcn_mfma_f32_16x16x32_bf16(a, b0, accZ0, 0, 0, 0);
        accZ1 = __builtin_amdgcn_mfma_f32_16x16x32_bf16(a, b1, accZ1, 0, 0, 0);
    }
#pragma unroll
    for (int r = 0; r < 4; ++r) {
        int jj = ((lane >> 4) << 2) + r;
        zsl[wv][jj][lr]      = accZ0[r];
        zsl[wv][jj][lr + 16] = accZ1[r];
    }
    __syncthreads();

#pragma unroll
    for (int rep = 0; rep < 2; ++rep) {
        int p = (rep << 8) + tid;
        int j = p >> 5, b = p & 31;
        int n0 = j0 + j;
        float zi = xwT[(long)n0 * 32 + b]            + zsl[0][j][b] + bU[n0];
        float zf = xwT[(long)(HH + n0) * 32 + b]     + zsl[1][j][b] + bU[HH + n0];
        float zo = xwT[(long)(2 * HH + n0) * 32 + b] + zsl[2][j][b] + bU[2 * HH + n0];
        float zg = xwT[(long)(3 * HH + n0) * 32 + b] + zsl[3][j][b] + bU[3 * HH + n0];
        float ig = 1.f / (1.f + expf(-zi));
        float fg = 1.f / (1.f + expf(-zf));
        float og = 1.f / (1.f + expf(-zo));
        float g  = tanhf(zg);
        float cold = cst[(long)b * HH + n0];
        float cn = alpha[n0] * (fg * cold + ig * g);
        float hn = og * tanhf(cn);
        cst[(long)b * HH + n0]  = cn;
        hout[(long)b * HH + n0] = f2bf(hn);
        out1t[(long)b * HH + n0] = hn;
    }
}

// ---------------------------------------------------------------------------
// mLSTM step, MFMA edition. Same as slstm_step2 plus: each wave also computes
// an s-tile s[wv*16..+15][b] = Bm·h^T redundantly per block (fuses mlstm_q),
// then q = xa*s in LDS, then low-rank mix in the epilogue.
// ---------------------------------------------------------------------------
__global__ __launch_bounds__(256) void mlstm_step2(
    const float* __restrict__ xwT,           // [4096][32] fp32 (incl. bWm)
    const unsigned short* __restrict__ Ubf,  // Um bf16
    const float* __restrict__ bU,
    const float* __restrict__ Pmat,          // [1024][64] fp32
    const unsigned short* __restrict__ Bmbf, // [64][1024] bf16
    const float* __restrict__ xaT,           // [64][32] fp32 for this tt
    const unsigned short* __restrict__ hin,
    unsigned short* __restrict__ hout,
    float* __restrict__ cst,
    float* __restrict__ out,                 // [B][T][H] fp32
    int t)
{
    __shared__ __align__(16) unsigned short hs[32 * 1024]; // 64 KB
    __shared__ float zsl[4][16][32];                       // 8 KB
    __shared__ float ssl[64][32];                          // 8 KB
    const int tid  = threadIdx.x;
    const int lane = tid & 63, wv = tid >> 6;
    const int j0   = blockIdx.x * 16;
    const int lr   = lane & 15;
    const int koff = (lane >> 4) << 3;

    const uint4* hg = (const uint4*)hin;
#pragma unroll
    for (int i = 0; i < 16; ++i) {
        int u = tid + (i << 8);
        int o = u << 4;
        int sw = o ^ (((o >> 11) & 7) << 4);
        *(uint4*)((char*)hs + sw) = hg[u];
    }
    __syncthreads();

    const unsigned short* Arow =
        Ubf + (((long)(wv * HH + j0 + lr)) << 10) + koff;
    const unsigned short* Brow =
        Bmbf + (((long)(wv * 16 + lr)) << 10) + koff;
    const int base0 = lr * 2048 + koff * 2;
    const int base1 = (lr + 16) * 2048 + koff * 2;
    const int swz   = (lr & 7) << 4;

    f32x4 accZ0 = {0.f, 0.f, 0.f, 0.f}, accZ1 = {0.f, 0.f, 0.f, 0.f};
    f32x4 accS0 = {0.f, 0.f, 0.f, 0.f}, accS1 = {0.f, 0.f, 0.f, 0.f};
#pragma unroll 4
    for (int k0 = 0; k0 < 1024; k0 += 32) {
        bf16x8 a  = *(const bf16x8*)(Arow + k0);
        bf16x8 s  = *(const bf16x8*)(Brow + k0);
        bf16x8 b0 = *(const bf16x8*)((const char*)hs + ((base0 + k0 * 2) ^ swz));
        bf16x8 b1 = *(const bf16x8*)((const char*)hs + ((base1 + k0 * 2) ^ swz));
        accZ0 = __builtin_amdgcn_mfma_f32_16x16x32_bf16(a, b0, accZ0, 0, 0, 0);
        accZ1 = __builtin_amdgcn_mfma_f32_16x16x32_bf16(a, b1, accZ1, 0, 0, 0);
        accS0 = __builtin_amdgcn_mfma_f32_16x16x32_bf16(s, b0, accS0, 0, 0, 0);
        accS1 = __builtin_amdgcn_mfma_f32_16x16x32_bf16(s, b1, accS1, 0, 0, 0);
    }
#pragma unroll
    for (int r = 0; r < 4; ++r) {
        int jj = ((lane >> 4) << 2) + r;
        zsl[wv][jj][lr]           = accZ0[r];
        zsl[wv][jj][lr + 16]      = accZ1[r];
        ssl[wv * 16 + jj][lr]      = accS0[r];
        ssl[wv * 16 + jj][lr + 16] = accS1[r];
    }
    __syncthreads();

    // q[r][b] = xa[r][b] * s[r][b], in place
#pragma unroll
    for (int i = 0; i < 8; ++i) {
        int idx = tid + (i << 8);
        ((float*)ssl)[idx] *= xaT[idx];
    }
    __syncthreads();

#pragma unroll
    for (int rep = 0; rep < 2; ++rep) {
        int p = (rep << 8) + tid;
        int j = p >> 5, b = p & 31;
        int n0 = j0 + j;
        float zi = xwT[(long)n0 * 32 + b]            + zsl[0][j][b] + bU[n0];
        float zf = xwT[(long)(HH + n0) * 32 + b]     + zsl[1][j][b] + bU[HH + n0];
        float zo = xwT[(long)(2 * HH + n0) * 32 + b] + zsl[2][j][b] + bU[2 * HH + n0];
        float zg = xwT[(long)(3 * HH + n0) * 32 + b] + zsl[3][j][b] + bU[3 * HH + n0];
        float ig = 1.f / (1.f + expf(-zi));
        float fg = 1.f / (1.f + expf(-zf));
        float og = 1.f / (1.f + expf(-zo));
        float g  = tanhf(zg);
        const float* Pj = Pmat + (long)n0 * 64;
        float mx = 0.f;
#pragma unroll
        for (int r = 0; r < 64; ++r) mx += Pj[r] * ssl[r][b];
        float cold = cst[(long)b * HH + n0];
        float cn = fg * cold + ig * g + 0.1f * mx;
        float hn = og * tanhf(cn);
        cst[(long)b * HH + n0]  = cn;
        hout[(long)b * HH + n0] = f2bf(hn);
        out[(long)b * (TT_ * HH) + (long)t * HH + n0] = hn;
    }
}

// ---------------------------------------------------------------------------
// Launch. Per-step kernels (no cooperative launch). ~39 MB workspace.
// ---------------------------------------------------------------------------
extern "C" void kernel_launch(void* const* d_in, const int* in_sizes, int n_in,
                              void* d_out, int out_size, void* d_ws, size_t ws_size,
                              hipStream_t stream) {
    const float* x     = (const float*)d_in[0];
    const float* Ws    = (const float*)d_in[1];
    const float* bWs   = (const float*)d_in[2];
    const float* Us    = (const float*)d_in[3];
    const float* bUs   = (const float*)d_in[4];
    const float* alpha = (const float*)d_in[5];
    const float* Wm    = (const float*)d_in[6];
    const float* bWm   = (const float*)d_in[7];
    const float* Um    = (const float*)d_in[8];
    const float* bUm   = (const float*)d_in[9];
    const float* A     = (const float*)d_in[10];
    const float* Bm    = (const float*)d_in[11];
    const float* P     = (const float*)d_in[12];
    float* out = (float*)d_out;

    float* w      = (float*)d_ws;
    float* xwT    = w;                               // TC*4H*32   = 4,194,304 f
    float* out1c  = xwT + (long)TC * FH * 32;        // TC*B*H     = 1,048,576 f
    float* xaT    = out1c + (long)TC * BB * HH;      // TC*R*32    = 65,536 f
    unsigned short* UbfS = (unsigned short*)(xaT + (long)TC * RR_ * 32); // 4M bf16
    unsigned short* UbfM = UbfS + (long)FH * HH;     // 4M bf16
    unsigned short* Bmbf = UbfM + (long)FH * HH;     // 64K bf16
    float* st     = (float*)(Bmbf + (long)RR_ * HH); // state region (zeroed):
    unsigned short* hbsA = (unsigned short*)st;          // 32K bf16 = 16,384 f
    unsigned short* hbsB = hbsA + BB * HH;
    unsigned short* hbmA = hbsB + BB * HH;
    unsigned short* hbmB = hbmA + BB * HH;
    float* cS     = (float*)(hbmB + BB * HH);        // 32,768 f
    float* cM     = cS + BB * HH;                    // 32,768 f
    // total ~9.67M floats = 38.7 MB

    // zero states: 4*16384 + 2*32768 = 131,072 floats = 32,768 float4
    init_zero<<<128, 256, 0, stream>>>((float4*)st, 32768);

    // one-time bf16 conversion of recurrent weights
    cvt_bf16<<<2048, 256, 0, stream>>>(Us, UbfS, FH * HH / 4);
    cvt_bf16<<<2048, 256, 0, stream>>>(Um, UbfM, FH * HH / 4);
    cvt_bf16<<<64,   256, 0, stream>>>(Bm, Bmbf, RR_ * HH / 4);

    dim3 gbig(FH / 128, (TC * BB) / 64);   // (32, 16)
    dim3 gxa(RR_ / 64, (TC * BB) / 64);    // (1, 16)

    for (int ch = 0; ch < TT_ / TC; ++ch) {
        const int t0 = ch * TC;

        // ---- sLSTM input proj: xwT[tt][n][b] = x @ Ws.T + bWs ----
        gemm_mfma<64, 128><<<gbig, 256, 0, stream>>>(
            x + (long)t0 * DD, (long)DD, (long)TT_ * DD, Ws, bWs,
            xwT, TC * BB, FH, DD);

        for (int tt = 0; tt < TC; ++tt) {
            const unsigned short* hin = (tt & 1) ? hbsB : hbsA;
            unsigned short* hout      = (tt & 1) ? hbsA : hbsB;
            slstm_step2<<<64, 256, 0, stream>>>(
                xwT + (long)tt * FH * 32, UbfS, bUs, alpha,
                hin, hout, cS, out1c + (long)tt * BB * HH);
        }

        // ---- mLSTM projections ----
        gemm_mfma<64, 128><<<gbig, 256, 0, stream>>>(
            out1c, (long)BB * HH, (long)HH, Wm, bWm,
            xwT, TC * BB, FH, HH);
        gemm_mfma<64, 64><<<gxa, 256, 0, stream>>>(
            out1c, (long)BB * HH, (long)HH, A, nullptr,
            xaT, TC * BB, RR_, HH);

        // ---- mLSTM scan (q fused in-kernel) ----
        for (int tt = 0; tt < TC; ++tt) {
            const int t = t0 + tt;
            const unsigned short* hin = (tt & 1) ? hbmB : hbmA;
            unsigned short* hout      = (tt & 1) ? hbmA : hbmB;
            mlstm_step2<<<64, 256, 0, stream>>>(
                xwT + (long)tt * FH * 32, UbfM, bUm, P, Bmbf,
                xaT + (long)tt * RR_ * 32,
                hin, hout, cM, out, t);
        }
    }
}

// Round 4
// 8725.630 us; speedup vs baseline: 13.4582x; 1.4675x over previous
//
#include <hip/hip_runtime.h>

// Problem constants
#define BB   32      // batch
#define TT_  512     // sequence length
#define DD   1024    // input dim
#define HH   1024    // hidden
#define RR_  64      // low-rank
#define FH   4096    // 4*H
#define TC   32      // timestep chunk

typedef __attribute__((ext_vector_type(8))) short          bf16x8;   // MFMA A/B frag
typedef __attribute__((ext_vector_type(4))) float          f32x4;    // MFMA C/D frag
typedef __attribute__((ext_vector_type(4))) unsigned short us4;

// fp32 -> bf16 bits, round-to-nearest-even
__device__ __forceinline__ unsigned short f2bf(float x) {
    union { float f; unsigned u; } v; v.f = x;
    return (unsigned short)((v.u + 0x7FFFu + ((v.u >> 16) & 1u)) >> 16);
}

// ---------------------------------------------------------------------------
// Zero-init (ws poisoned 0xAA before every call)
// ---------------------------------------------------------------------------
__global__ void init_zero(float4* p, int n4) {
    int i = blockIdx.x * blockDim.x + threadIdx.x;
    if (i < n4) p[i] = make_float4(0.f, 0.f, 0.f, 0.f);
}

// fp32 -> bf16 bulk convert (U matrices / Bm, once per call)
__global__ void cvt_bf16(const float* __restrict__ src,
                         unsigned short* __restrict__ dst, int n4) {
    int i = blockIdx.x * blockDim.x + threadIdx.x;
    int stride = gridDim.x * blockDim.x;
    for (; i < n4; i += stride) {
        float4 v = ((const float4*)src)[i];
        us4 t; t.x = f2bf(v.x); t.y = f2bf(v.y); t.z = f2bf(v.z); t.w = f2bf(v.w);
        ((us4*)dst)[i] = t;
    }
}

// ---------------------------------------------------------------------------
// bf16-MFMA GEMM, fp32 I/O, TRANSPOSED output: C[(m>>5)*N + n)*32 + (m&31)]
// Row m = tt*32 + b ; rowptr = Abase + (m>>5)*strideT + (m&31)*strideB
// ---------------------------------------------------------------------------
template<int BM, int BN>
__global__ __launch_bounds__(256) void gemm_mfma(
    const float* __restrict__ Abase, long strideT, long strideB,
    const float* __restrict__ W, const float* __restrict__ bias,
    float* __restrict__ C, int M, int N, int K)
{
    constexpr int BK  = 32;
    constexpr int WTM = BM / 2, WTN = BN / 2;
    constexpr int MI  = WTM / 16, NI = WTN / 16;
    constexpr int AU  = BM * (BK / 4) / 256;
    constexpr int BU  = BN * (BK / 4) / 256;

    __shared__ __align__(16) unsigned short As[BM * BK];
    __shared__ __align__(16) unsigned short Bs[BN * BK];

    const int tid  = threadIdx.x;
    const int lane = tid & 63, wave = tid >> 6;
    const int wm   = wave >> 1, wn = wave & 1;
    const int kg   = lane >> 4;
    const int lr   = lane & 15;
    const long bm  = (long)blockIdx.y * BM;
    const long bn  = (long)blockIdx.x * BN;

    const float* ag[AU]; int alds[AU];
    const float* bg[BU]; int blds[BU];
#pragma unroll
    for (int i = 0; i < AU; ++i) {
        int u = i * 256 + tid, row = u >> 3, uc = u & 7;
        long m = bm + row;
        ag[i]   = Abase + (m >> 5) * strideT + (m & 31) * strideB + uc * 4;
        alds[i] = row * BK + uc * 4;
    }
#pragma unroll
    for (int i = 0; i < BU; ++i) {
        int u = i * 256 + tid, row = u >> 3, uc = u & 7;
        bg[i]   = W + (long)(bn + row) * K + uc * 4;
        blds[i] = row * BK + uc * 4;
    }

    f32x4 acc[MI][NI] = {};

    float4 av[AU], bv[BU];
#pragma unroll
    for (int i = 0; i < AU; ++i) av[i] = *(const float4*)(ag[i]);
#pragma unroll
    for (int i = 0; i < BU; ++i) bv[i] = *(const float4*)(bg[i]);

    for (int k0 = 0; k0 < K; k0 += BK) {
        __syncthreads();
#pragma unroll
        for (int i = 0; i < AU; ++i) {
            us4 t; t.x = f2bf(av[i].x); t.y = f2bf(av[i].y);
                   t.z = f2bf(av[i].z); t.w = f2bf(av[i].w);
            *(us4*)&As[alds[i]] = t;
        }
#pragma unroll
        for (int i = 0; i < BU; ++i) {
            us4 t; t.x = f2bf(bv[i].x); t.y = f2bf(bv[i].y);
                   t.z = f2bf(bv[i].z); t.w = f2bf(bv[i].w);
            *(us4*)&Bs[blds[i]] = t;
        }
        __syncthreads();

        if (k0 + BK < K) {
#pragma unroll
            for (int i = 0; i < AU; ++i) av[i] = *(const float4*)(ag[i] + k0 + BK);
#pragma unroll
            for (int i = 0; i < BU; ++i) bv[i] = *(const float4*)(bg[i] + k0 + BK);
        }

        bf16x8 af[MI], bfr[NI];
#pragma unroll
        for (int mi = 0; mi < MI; ++mi)
            af[mi] = *(const bf16x8*)&As[(wm * WTM + mi * 16 + lr) * BK + kg * 8];
#pragma unroll
        for (int ni = 0; ni < NI; ++ni)
            bfr[ni] = *(const bf16x8*)&Bs[(wn * WTN + ni * 16 + lr) * BK + kg * 8];
#pragma unroll
        for (int mi = 0; mi < MI; ++mi)
#pragma unroll
            for (int ni = 0; ni < NI; ++ni)
                acc[mi][ni] = __builtin_amdgcn_mfma_f32_16x16x32_bf16(
                    af[mi], bfr[ni], acc[mi][ni], 0, 0, 0);
    }

    const int rbase = (lane >> 4) * 4;
#pragma unroll
    for (int mi = 0; mi < MI; ++mi) {
        long m0 = bm + wm * WTM + mi * 16 + rbase;
        long tt = m0 >> 5; int bq = (int)(m0 & 31);
#pragma unroll
        for (int ni = 0; ni < NI; ++ni) {
            long n = bn + wn * WTN + ni * 16 + lr;
            float bia = bias ? bias[n] : 0.f;
            float4 v = make_float4(acc[mi][ni][0] + bia, acc[mi][ni][1] + bia,
                                   acc[mi][ni][2] + bia, acc[mi][ni][3] + bia);
            *(float4*)&C[(tt * N + n) * 32 + bq] = v;
        }
    }
}

// ---------------------------------------------------------------------------
// Scan-step bodies (identical math to round-3 kernels), LDS carved from smem.
// smem layout: [0,64K) h tile (swizzled) ; [64K,72K) zsl[4][16][32] ;
//              [72K,80K) ssl[64][32] (mLSTM only)
// ---------------------------------------------------------------------------
__device__ __forceinline__ void slstm_body(
    int bx, const float* __restrict__ xwT,
    const unsigned short* __restrict__ Ubf, const float* __restrict__ bU,
    const float* __restrict__ alpha, const unsigned short* __restrict__ hin,
    unsigned short* __restrict__ hout, float* __restrict__ cst,
    float* __restrict__ out1t, char* smem)
{
    unsigned short* hs = (unsigned short*)smem;
    float* zsl = (float*)(smem + 65536);           // [wv][jj][b] = wv*512+jj*32+b
    const int tid  = threadIdx.x;
    const int lane = tid & 63, wv = tid >> 6;
    const int j0   = bx * 16;
    const int lr   = lane & 15;
    const int koff = (lane >> 4) << 3;

    const uint4* hg = (const uint4*)hin;
#pragma unroll
    for (int i = 0; i < 16; ++i) {
        int u = tid + (i << 8);
        int o = u << 4;
        int sw = o ^ (((o >> 11) & 7) << 4);
        *(uint4*)(smem + sw) = hg[u];
    }
    __syncthreads();

    const unsigned short* Arow = Ubf + (((long)(wv * HH + j0 + lr)) << 10) + koff;
    const int base0 = lr * 2048 + koff * 2;
    const int base1 = (lr + 16) * 2048 + koff * 2;
    const int swz   = (lr & 7) << 4;

    f32x4 accZ0 = {0.f, 0.f, 0.f, 0.f}, accZ1 = {0.f, 0.f, 0.f, 0.f};
#pragma unroll 4
    for (int k0 = 0; k0 < 1024; k0 += 32) {
        bf16x8 a  = *(const bf16x8*)(Arow + k0);
        bf16x8 b0 = *(const bf16x8*)(smem + ((base0 + k0 * 2) ^ swz));
        bf16x8 b1 = *(const bf16x8*)(smem + ((base1 + k0 * 2) ^ swz));
        accZ0 = __builtin_amdgcn_mfma_f32_16x16x32_bf16(a, b0, accZ0, 0, 0, 0);
        accZ1 = __builtin_amdgcn_mfma_f32_16x16x32_bf16(a, b1, accZ1, 0, 0, 0);
    }
#pragma unroll
    for (int r = 0; r < 4; ++r) {
        int jj = ((lane >> 4) << 2) + r;
        zsl[wv * 512 + jj * 32 + lr]      = accZ0[r];
        zsl[wv * 512 + jj * 32 + lr + 16] = accZ1[r];
    }
    __syncthreads();

#pragma unroll
    for (int rep = 0; rep < 2; ++rep) {
        int p = (rep << 8) + tid;
        int j = p >> 5, b = p & 31;
        int n0 = j0 + j;
        float zi = xwT[(long)n0 * 32 + b]            + zsl[j * 32 + b]        + bU[n0];
        float zf = xwT[(long)(HH + n0) * 32 + b]     + zsl[512 + j * 32 + b]  + bU[HH + n0];
        float zo = xwT[(long)(2 * HH + n0) * 32 + b] + zsl[1024 + j * 32 + b] + bU[2 * HH + n0];
        float zg = xwT[(long)(3 * HH + n0) * 32 + b] + zsl[1536 + j * 32 + b] + bU[3 * HH + n0];
        float ig = 1.f / (1.f + expf(-zi));
        float fg = 1.f / (1.f + expf(-zf));
        float og = 1.f / (1.f + expf(-zo));
        float g  = tanhf(zg);
        float cold = cst[(long)b * HH + n0];
        float cn = alpha[n0] * (fg * cold + ig * g);
        float hn = og * tanhf(cn);
        cst[(long)b * HH + n0]  = cn;
        hout[(long)b * HH + n0] = f2bf(hn);
        out1t[(long)b * HH + n0] = hn;
    }
}

__device__ __forceinline__ void mlstm_body(
    int bx, const float* __restrict__ xwT,
    const unsigned short* __restrict__ Ubf, const float* __restrict__ bU,
    const float* __restrict__ Pmat, const unsigned short* __restrict__ Bmbf,
    const float* __restrict__ xaT, const unsigned short* __restrict__ hin,
    unsigned short* __restrict__ hout, float* __restrict__ cst,
    float* __restrict__ out, int t, char* smem)
{
    unsigned short* hs = (unsigned short*)smem;
    float* zsl = (float*)(smem + 65536);           // [4][16][32]
    float* ssl = (float*)(smem + 65536 + 8192);    // [64][32]
    const int tid  = threadIdx.x;
    const int lane = tid & 63, wv = tid >> 6;
    const int j0   = bx * 16;
    const int lr   = lane & 15;
    const int koff = (lane >> 4) << 3;

    const uint4* hg = (const uint4*)hin;
#pragma unroll
    for (int i = 0; i < 16; ++i) {
        int u = tid + (i << 8);
        int o = u << 4;
        int sw = o ^ (((o >> 11) & 7) << 4);
        *(uint4*)(smem + sw) = hg[u];
    }
    __syncthreads();

    const unsigned short* Arow = Ubf + (((long)(wv * HH + j0 + lr)) << 10) + koff;
    const unsigned short* Brow = Bmbf + (((long)(wv * 16 + lr)) << 10) + koff;
    const int base0 = lr * 2048 + koff * 2;
    const int base1 = (lr + 16) * 2048 + koff * 2;
    const int swz   = (lr & 7) << 4;

    f32x4 accZ0 = {0.f, 0.f, 0.f, 0.f}, accZ1 = {0.f, 0.f, 0.f, 0.f};
    f32x4 accS0 = {0.f, 0.f, 0.f, 0.f}, accS1 = {0.f, 0.f, 0.f, 0.f};
#pragma unroll 4
    for (int k0 = 0; k0 < 1024; k0 += 32) {
        bf16x8 a  = *(const bf16x8*)(Arow + k0);
        bf16x8 s  = *(const bf16x8*)(Brow + k0);
        bf16x8 b0 = *(const bf16x8*)(smem + ((base0 + k0 * 2) ^ swz));
        bf16x8 b1 = *(const bf16x8*)(smem + ((base1 + k0 * 2) ^ swz));
        accZ0 = __builtin_amdgcn_mfma_f32_16x16x32_bf16(a, b0, accZ0, 0, 0, 0);
        accZ1 = __builtin_amdgcn_mfma_f32_16x16x32_bf16(a, b1, accZ1, 0, 0, 0);
        accS0 = __builtin_amdgcn_mfma_f32_16x16x32_bf16(s, b0, accS0, 0, 0, 0);
        accS1 = __builtin_amdgcn_mfma_f32_16x16x32_bf16(s, b1, accS1, 0, 0, 0);
    }
#pragma unroll
    for (int r = 0; r < 4; ++r) {
        int jj = ((lane >> 4) << 2) + r;
        zsl[wv * 512 + jj * 32 + lr]      = accZ0[r];
        zsl[wv * 512 + jj * 32 + lr + 16] = accZ1[r];
        ssl[(wv * 16 + jj) * 32 + lr]      = accS0[r];
        ssl[(wv * 16 + jj) * 32 + lr + 16] = accS1[r];
    }
    __syncthreads();

    // q[r][b] = xa[r][b] * s[r][b], in place
#pragma unroll
    for (int i = 0; i < 8; ++i) {
        int idx = tid + (i << 8);
        ssl[idx] *= xaT[idx];
    }
    __syncthreads();

#pragma unroll
    for (int rep = 0; rep < 2; ++rep) {
        int p = (rep << 8) + tid;
        int j = p >> 5, b = p & 31;
        int n0 = j0 + j;
        float zi = xwT[(long)n0 * 32 + b]            + zsl[j * 32 + b]        + bU[n0];
        float zf = xwT[(long)(HH + n0) * 32 + b]     + zsl[512 + j * 32 + b]  + bU[HH + n0];
        float zo = xwT[(long)(2 * HH + n0) * 32 + b] + zsl[1024 + j * 32 + b] + bU[2 * HH + n0];
        float zg = xwT[(long)(3 * HH + n0) * 32 + b] + zsl[1536 + j * 32 + b] + bU[3 * HH + n0];
        float ig = 1.f / (1.f + expf(-zi));
        float fg = 1.f / (1.f + expf(-zf));
        float og = 1.f / (1.f + expf(-zo));
        float g  = tanhf(zg);
        const float* Pj = Pmat + (long)n0 * 64;
        float mx = 0.f;
#pragma unroll
        for (int r = 0; r < 64; ++r) mx += Pj[r] * ssl[r * 32 + b];
        float cold = cst[(long)b * HH + n0];
        float cn = fg * cold + ig * g + 0.1f * mx;
        float hn = og * tanhf(cn);
        cst[(long)b * HH + n0]  = cn;
        hout[(long)b * HH + n0] = f2bf(hn);
        out[(long)b * (TT_ * HH) + (long)t * HH + n0] = hn;
    }
}

// ---------------------------------------------------------------------------
// Fused pipelined step: blocks 0-63 run sLSTM step of chunk ch; blocks 64-127
// run mLSTM step of chunk ch-1. The two halves are data-independent.
// ---------------------------------------------------------------------------
__global__ __launch_bounds__(256) void fused_step(
    // sLSTM
    const float* __restrict__ xwTs, const unsigned short* __restrict__ UbfS,
    const float* __restrict__ bUs, const float* __restrict__ alpha,
    const unsigned short* __restrict__ hsin, unsigned short* __restrict__ hsout,
    float* __restrict__ cS, float* __restrict__ out1t,
    // mLSTM
    const float* __restrict__ xwTm, const unsigned short* __restrict__ UbfM,
    const float* __restrict__ bUm, const float* __restrict__ Pmat,
    const unsigned short* __restrict__ Bmbf, const float* __restrict__ xaT,
    const unsigned short* __restrict__ hmin, unsigned short* __restrict__ hmout,
    float* __restrict__ cM, float* __restrict__ out, int t,
    int do_s, int do_m)
{
    __shared__ __align__(16) char smem[81920];  // 80 KB
    const int bx = blockIdx.x;
    if (bx < 64) {
        if (do_s)
            slstm_body(bx, xwTs, UbfS, bUs, alpha, hsin, hsout, cS, out1t, smem);
    } else {
        if (do_m)
            mlstm_body(bx - 64, xwTm, UbfM, bUm, Pmat, Bmbf, xaT,
                       hmin, hmout, cM, out, t, smem);
    }
}

// ---------------------------------------------------------------------------
// Launch: software-pipelined chunks. ~55 MB workspace.
// ---------------------------------------------------------------------------
extern "C" void kernel_launch(void* const* d_in, const int* in_sizes, int n_in,
                              void* d_out, int out_size, void* d_ws, size_t ws_size,
                              hipStream_t stream) {
    const float* x     = (const float*)d_in[0];
    const float* Ws    = (const float*)d_in[1];
    const float* bWs   = (const float*)d_in[2];
    const float* Us    = (const float*)d_in[3];
    const float* bUs   = (const float*)d_in[4];
    const float* alpha = (const float*)d_in[5];
    const float* Wm    = (const float*)d_in[6];
    const float* bWm   = (const float*)d_in[7];
    const float* Um    = (const float*)d_in[8];
    const float* bUm   = (const float*)d_in[9];
    const float* A     = (const float*)d_in[10];
    const float* Bm    = (const float*)d_in[11];
    const float* P     = (const float*)d_in[12];
    float* out = (float*)d_out;

    float* w      = (float*)d_ws;
    float* xwTs   = w;                               // TC*4H*32 = 4,194,304 f
    float* xwTm   = xwTs + (long)TC * FH * 32;       // TC*4H*32 = 4,194,304 f
    float* out1c  = xwTm + (long)TC * FH * 32;       // TC*B*H   = 1,048,576 f
    float* xaT    = out1c + (long)TC * BB * HH;      // TC*R*32  = 65,536 f
    unsigned short* UbfS = (unsigned short*)(xaT + (long)TC * RR_ * 32); // 4M bf16
    unsigned short* UbfM = UbfS + (long)FH * HH;     // 4M bf16
    unsigned short* Bmbf = UbfM + (long)FH * HH;     // 64K bf16
    // zeroed state region (contiguous): 4 h-bufs (bf16) + 2 c-bufs (fp32)
    unsigned short* hbsA = Bmbf + (long)RR_ * HH;
    unsigned short* hbsB = hbsA + BB * HH;
    unsigned short* hbmA = hbsB + BB * HH;
    unsigned short* hbmB = hbmA + BB * HH;
    float* cS     = (float*)(hbmB + BB * HH);
    float* cM     = cS + BB * HH;
    // state bytes: 4*64KB + 2*128KB = 512 KB = 32768 float4

    init_zero<<<128, 256, 0, stream>>>((float4*)hbsA, 32768);

    cvt_bf16<<<2048, 256, 0, stream>>>(Us, UbfS, FH * HH / 4);
    cvt_bf16<<<2048, 256, 0, stream>>>(Um, UbfM, FH * HH / 4);
    cvt_bf16<<<64,   256, 0, stream>>>(Bm, Bmbf, RR_ * HH / 4);

    dim3 gbig(FH / 128, (TC * BB) / 64);   // (32, 16)
    dim3 gxa(RR_ / 64, (TC * BB) / 64);    // (1, 16)
    const int NC = TT_ / TC;               // 16

    for (int ch = 0; ch <= NC; ++ch) {
        const int do_s = (ch < NC), do_m = (ch > 0);

        // ---- sLSTM input proj for chunk ch ----
        if (do_s)
            gemm_mfma<64, 128><<<gbig, 256, 0, stream>>>(
                x + (long)(ch * TC) * DD, (long)DD, (long)TT_ * DD, Ws, bWs,
                xwTs, TC * BB, FH, DD);

        // ---- pipelined scan: sLSTM(ch) || mLSTM(ch-1) ----
        for (int tt = 0; tt < TC; ++tt) {
            const unsigned short* hsin = (tt & 1) ? hbsB : hbsA;
            unsigned short* hsout      = (tt & 1) ? hbsA : hbsB;
            const unsigned short* hmin = (tt & 1) ? hbmB : hbmA;
            unsigned short* hmout      = (tt & 1) ? hbmA : hbmB;
            fused_step<<<128, 256, 0, stream>>>(
                xwTs + (long)tt * FH * 32, UbfS, bUs, alpha,
                hsin, hsout, cS, out1c + (long)tt * BB * HH,
                xwTm + (long)tt * FH * 32, UbfM, bUm, P, Bmbf,
                xaT + (long)tt * RR_ * 32,
                hmin, hmout, cM, out, (ch - 1) * TC + tt,
                do_s, do_m);
        }

        // ---- mLSTM projections for chunk ch (consumed next iteration) ----
        if (do_s) {
            gemm_mfma<64, 128><<<gbig, 256, 0, stream>>>(
                out1c, (long)BB * HH, (long)HH, Wm, bWm,
                xwTm, TC * BB, FH, HH);
            gemm_mfma<64, 64><<<gxa, 256, 0, stream>>>(
                out1c, (long)BB * HH, (long)HH, A, nullptr,
                xaT, TC * BB, RR_, HH);
        }
    }
}